// Round 1
// baseline (7518.197 us; speedup 1.0000x reference)
//
#include <hip/hip_runtime.h>

#define T_STEPS 2048
#define BATCH   16
#define DIM     1024
#define RANK    64
#define BD      (BATCH * DIM)        // 16384
#define ROWS    (T_STEPS * BATCH)    // 32768

// ---------------------------------------------------------------------------
// K1: Y[row][0:64] = x_row . V_x^T ; Y[row][64:128] = x_row . V_z^T
// row = t*16+b. Tiled f32 GEMM: M_TILE=64, N=128, K chunks of 64.
// ---------------------------------------------------------------------------
__global__ __launch_bounds__(256) void k_proj1(const float* __restrict__ x,
                                               const float* __restrict__ Vx,
                                               const float* __restrict__ Vz,
                                               float* __restrict__ Y) {
  __shared__ __align__(16) float Xs[64][64];    // [k][m] 16KB
  __shared__ __align__(16) float Vs[64][128];   // [k][n] 32KB
  const int tid = threadIdx.x;
  const int m0 = blockIdx.x * 64;
  const int ty = tid >> 4;   // m group (16 groups of 4 rows)
  const int tx = tid & 15;   // n group (16 groups of 8 cols)

  float acc[4][8];
#pragma unroll
  for (int i = 0; i < 4; ++i)
#pragma unroll
    for (int j = 0; j < 8; ++j) acc[i][j] = 0.f;

  const int la = tid & 63;   // X loader: row
  const int lb = tid >> 6;   // X loader: k sub-block 0..3
  const int vn = tid & 127;  // V loader: n row
  const int vk = tid >> 7;   // V loader: k half 0..1
  const float* vsrc = (vn < 64) ? (Vx + (size_t)vn * DIM) : (Vz + (size_t)(vn - 64) * DIM);

  for (int kc = 0; kc < DIM; kc += 64) {
    __syncthreads();
#pragma unroll
    for (int q = 0; q < 4; ++q) {
      const float4 v = *reinterpret_cast<const float4*>(x + (size_t)(m0 + la) * DIM + kc + lb * 16 + q * 4);
      const int k = lb * 16 + q * 4;
      Xs[k + 0][la] = v.x; Xs[k + 1][la] = v.y; Xs[k + 2][la] = v.z; Xs[k + 3][la] = v.w;
    }
#pragma unroll
    for (int q = 0; q < 8; ++q) {
      const float4 v = *reinterpret_cast<const float4*>(vsrc + kc + vk * 32 + q * 4);
      const int k = vk * 32 + q * 4;
      Vs[k + 0][vn] = v.x; Vs[k + 1][vn] = v.y; Vs[k + 2][vn] = v.z; Vs[k + 3][vn] = v.w;
    }
    __syncthreads();
#pragma unroll 8
    for (int k = 0; k < 64; ++k) {
      const float4 xm = *reinterpret_cast<const float4*>(&Xs[k][ty * 4]);      // broadcast (16 lanes share)
      const float4 v0 = *reinterpret_cast<const float4*>(&Vs[k][tx * 8]);
      const float4 v1 = *reinterpret_cast<const float4*>(&Vs[k][tx * 8 + 4]);
      const float xs[4] = {xm.x, xm.y, xm.z, xm.w};
      const float vs[8] = {v0.x, v0.y, v0.z, v0.w, v1.x, v1.y, v1.z, v1.w};
#pragma unroll
      for (int i = 0; i < 4; ++i)
#pragma unroll
        for (int j = 0; j < 8; ++j) acc[i][j] = fmaf(xs[i], vs[j], acc[i][j]);
    }
  }
#pragma unroll
  for (int i = 0; i < 4; ++i) {
    float* dst = Y + (size_t)(m0 + ty * 4 + i) * 128 + tx * 8;
    float4 o0 = {acc[i][0], acc[i][1], acc[i][2], acc[i][3]};
    float4 o1 = {acc[i][4], acc[i][5], acc[i][6], acc[i][7]};
    *reinterpret_cast<float4*>(dst) = o0;
    *reinterpret_cast<float4*>(dst + 4) = o1;
  }
}

// ---------------------------------------------------------------------------
// K2: ux[t,b,d] = Y[t,b,0:64].U_x[d,:] + bias[d]   -> staged into h slot t+1
//     gate[t,b,d] = silu(Y[t,b,64:128].U_z[d,:])   -> staged into out slot t
// grid (T, 8): blockIdx.y 0..3 -> ux cols, 4..7 -> gate cols. 256 cols/block.
// ---------------------------------------------------------------------------
__global__ __launch_bounds__(256) void k_proj2(const float* __restrict__ Y,
                                               const float* __restrict__ Ux,
                                               const float* __restrict__ Uz,
                                               const float* __restrict__ bias,
                                               float* __restrict__ outbase) {
  __shared__ __align__(16) float Ys[16][64];
  const int t = blockIdx.x;
  const int j = blockIdx.y;
  const bool is_z = (j >= 4);
  const int col = (is_z ? (j - 4) : j) * 256 + threadIdx.x;
  const int roff = is_z ? 64 : 0;
  {
    const int b = threadIdx.x >> 4, rq = threadIdx.x & 15;
    const float4 v = *reinterpret_cast<const float4*>(Y + (size_t)(t * BATCH + b) * 128 + roff + rq * 4);
    *reinterpret_cast<float4*>(&Ys[b][rq * 4]) = v;
  }
  const float* up = (is_z ? Uz : Ux) + (size_t)col * RANK;
  float4 Uc[16];
#pragma unroll
  for (int q = 0; q < 16; ++q) Uc[q] = *reinterpret_cast<const float4*>(up + q * 4);
  __syncthreads();

  float acc[16];
#pragma unroll
  for (int b = 0; b < 16; ++b) acc[b] = 0.f;
#pragma unroll
  for (int q = 0; q < 16; ++q) {
    const float4 u = Uc[q];
#pragma unroll
    for (int b = 0; b < 16; ++b) {
      const float4 y = *reinterpret_cast<const float4*>(&Ys[b][q * 4]);  // uniform addr -> broadcast
      acc[b] = fmaf(u.x, y.x, fmaf(u.y, y.y, fmaf(u.z, y.z, fmaf(u.w, y.w, acc[b]))));
    }
  }
  if (is_z) {
    float* g = outbase + (size_t)t * BD + col;               // gate into output section
#pragma unroll
    for (int b = 0; b < 16; ++b) {
      const float v = acc[b];
      g[(size_t)b * DIM] = v / (1.f + __expf(-v));           // silu
    }
  } else {
    const float bb = bias[col];
    float* u = outbase + (size_t)T_STEPS * BD + (size_t)(t + 1) * BD + col;  // ux (+bias) into h slot t+1
#pragma unroll
    for (int b = 0; b < 16; ++b) u[(size_t)b * DIM] = acc[b] + bb;
  }
}

// ---------------------------------------------------------------------------
// K3: sequential recurrence. 16 blocks (one per batch) x 1024 threads.
// h in LDS; U_h row per thread in 64 VGPRs; V_h slice 32 VGPR + 32 LDS.
// Raw s_barrier + lgkmcnt(0) (NOT __syncthreads) so the one-step-ahead
// ux/gate global prefetch stays in flight across barriers (no vmcnt(0) drain).
// ---------------------------------------------------------------------------
__device__ __forceinline__ float wave_sum63(float v) {
  // Full 64-lane sum, valid in lane 63. VALU-pipe DPP tree (no ds_swizzle).
  int x;
  x = __builtin_amdgcn_update_dpp(0, __float_as_int(v), 0x111, 0xf, 0xf, true); v += __int_as_float(x); // row_shr:1
  x = __builtin_amdgcn_update_dpp(0, __float_as_int(v), 0x112, 0xf, 0xf, true); v += __int_as_float(x); // row_shr:2
  x = __builtin_amdgcn_update_dpp(0, __float_as_int(v), 0x114, 0xf, 0xf, true); v += __int_as_float(x); // row_shr:4
  x = __builtin_amdgcn_update_dpp(0, __float_as_int(v), 0x118, 0xf, 0xf, true); v += __int_as_float(x); // row_shr:8
  x = __builtin_amdgcn_update_dpp(0, __float_as_int(v), 0x142, 0xa, 0xf, true); v += __int_as_float(x); // bcast15 rows 1,3
  x = __builtin_amdgcn_update_dpp(0, __float_as_int(v), 0x143, 0xc, 0xf, true); v += __int_as_float(x); // bcast31 rows 2,3
  return v;
}

__device__ __forceinline__ void bar_lds() {
  asm volatile("s_waitcnt lgkmcnt(0)" ::: "memory");
  __builtin_amdgcn_s_barrier();
}

__device__ __forceinline__ float tanh_fast(float x) {
  const float e = __expf(2.f * x);          // |arg| << 40 here, no overflow
  return (e - 1.f) / (e + 1.f);
}

__global__ __launch_bounds__(1024) void k_recur(const float* __restrict__ h0,
                                                const float* __restrict__ Uh,
                                                const float* __restrict__ Vh,
                                                float* __restrict__ outbase) {
  // LDS: 128KB V half + 4KB h + 256B r = 132.3KB (fits 160KB, 1 block/CU)
  __shared__ __align__(16) float Vlds[8][1024][4];
  __shared__ __align__(16) float hbuf[DIM];
  __shared__ __align__(16) float rbuf[RANK];

  const int tid = threadIdx.x;
  const int w = tid >> 6, l = tid & 63;
  const int b = blockIdx.x;

  float* outsec = outbase;                          // [T][B][D] (holds gate, overwritten with out)
  float* hsec   = outbase + (size_t)T_STEPS * BD;   // [T+1][B][D] (slots 1..T hold ux+bias)

  // U_h row for this thread's output dim: 64 floats in VGPRs
  float4 Ureg[16];
#pragma unroll
  for (int q = 0; q < 16; ++q)
    Ureg[q] = *reinterpret_cast<const float4*>(Uh + (size_t)tid * RANK + q * 4);

  // V_h slice: rows 4w+i, d = l + 64k. k<8 -> VGPR, k>=8 -> LDS [chunk][tid][4]
  float Vreg[4][8];
#pragma unroll
  for (int i = 0; i < 4; ++i) {
    const float* vr = Vh + (size_t)(4 * w + i) * DIM + l;
#pragma unroll
    for (int k = 0; k < 8; ++k) Vreg[i][k] = vr[64 * k];
#pragma unroll
    for (int g = 0; g < 2; ++g) {
      float4 t4;
      t4.x = vr[64 * (8 + 4 * g + 0)];
      t4.y = vr[64 * (8 + 4 * g + 1)];
      t4.z = vr[64 * (8 + 4 * g + 2)];
      t4.w = vr[64 * (8 + 4 * g + 3)];
      *reinterpret_cast<float4*>(&Vlds[i * 2 + g][tid][0]) = t4;
    }
  }

  const float hv0 = h0[(size_t)b * DIM + tid];
  hbuf[tid] = hv0;
  hsec[(size_t)b * DIM + tid] = hv0;                 // h[0] = h0

  const float* uxp = hsec + BD + (size_t)b * DIM + tid;      // ux(t) at h slot t+1
  const float* gtp = outsec + (size_t)b * DIM + tid;         // gate(t) at out slot t
  float ux_v = uxp[0];
  float gt_v = gtp[0];

  bar_lds();

  const float* hl = hbuf + l;
  for (int t = 0; t < T_STEPS; ++t) {
    // ---------- phase 1: r[64] = V_h . h ----------
    float acc0 = 0.f, acc1 = 0.f, acc2 = 0.f, acc3 = 0.f;
#pragma unroll
    for (int k = 0; k < 8; ++k) {
      const float hv = hl[64 * k];
      acc0 = fmaf(Vreg[0][k], hv, acc0);
      acc1 = fmaf(Vreg[1][k], hv, acc1);
      acc2 = fmaf(Vreg[2][k], hv, acc2);
      acc3 = fmaf(Vreg[3][k], hv, acc3);
    }
#pragma unroll
    for (int g = 0; g < 2; ++g) {
      float hv[4];
#pragma unroll
      for (int j = 0; j < 4; ++j) hv[j] = hl[64 * (8 + 4 * g + j)];
      {
        const float4 v = *reinterpret_cast<const float4*>(&Vlds[0 * 2 + g][tid][0]);
        acc0 = fmaf(v.x, hv[0], acc0); acc0 = fmaf(v.y, hv[1], acc0);
        acc0 = fmaf(v.z, hv[2], acc0); acc0 = fmaf(v.w, hv[3], acc0);
      }
      {
        const float4 v = *reinterpret_cast<const float4*>(&Vlds[1 * 2 + g][tid][0]);
        acc1 = fmaf(v.x, hv[0], acc1); acc1 = fmaf(v.y, hv[1], acc1);
        acc1 = fmaf(v.z, hv[2], acc1); acc1 = fmaf(v.w, hv[3], acc1);
      }
      {
        const float4 v = *reinterpret_cast<const float4*>(&Vlds[2 * 2 + g][tid][0]);
        acc2 = fmaf(v.x, hv[0], acc2); acc2 = fmaf(v.y, hv[1], acc2);
        acc2 = fmaf(v.z, hv[2], acc2); acc2 = fmaf(v.w, hv[3], acc2);
      }
      {
        const float4 v = *reinterpret_cast<const float4*>(&Vlds[3 * 2 + g][tid][0]);
        acc3 = fmaf(v.x, hv[0], acc3); acc3 = fmaf(v.y, hv[1], acc3);
        acc3 = fmaf(v.z, hv[2], acc3); acc3 = fmaf(v.w, hv[3], acc3);
      }
    }
    const float r0 = wave_sum63(acc0);
    const float r1 = wave_sum63(acc1);
    const float r2 = wave_sum63(acc2);
    const float r3 = wave_sum63(acc3);
    if (l == 63) {
      rbuf[4 * w + 0] = r0; rbuf[4 * w + 1] = r1;
      rbuf[4 * w + 2] = r2; rbuf[4 * w + 3] = r3;
    }
    bar_lds();

    // ---------- phase 2: h_new[d] = tanh(U_h[d,:].r + ux + bias) ----------
    float a = ux_v;   // bias already folded in by K2
#pragma unroll
    for (int q = 0; q < 16; ++q) {
      const float4 rr = *reinterpret_cast<const float4*>(&rbuf[q * 4]);  // broadcast
      const float4 u = Ureg[q];
      a = fmaf(u.x, rr.x, a); a = fmaf(u.y, rr.y, a);
      a = fmaf(u.z, rr.z, a); a = fmaf(u.w, rr.w, a);
    }
    const float hn = tanh_fast(a);

    hsec[(size_t)(t + 1) * BD + (size_t)b * DIM + tid] = hn;      // overwrites consumed ux slot
    outsec[(size_t)t * BD + (size_t)b * DIM + tid] = hn * gt_v;   // overwrites consumed gate slot

    if (t + 1 < T_STEPS) {            // one-step-ahead prefetch, stays in flight across barriers
      ux_v = uxp[(size_t)(t + 1) * BD];
      gt_v = gtp[(size_t)(t + 1) * BD];
    }
    hbuf[tid] = hn;
    bar_lds();
  }
}

extern "C" void kernel_launch(void* const* d_in, const int* in_sizes, int n_in,
                              void* d_out, int out_size, void* d_ws, size_t ws_size,
                              hipStream_t stream) {
  const float* x    = (const float*)d_in[0];
  const float* h0   = (const float*)d_in[1];
  const float* Uh   = (const float*)d_in[2];
  const float* Vh   = (const float*)d_in[3];
  const float* Ux   = (const float*)d_in[4];
  const float* Vx   = (const float*)d_in[5];
  const float* Uz   = (const float*)d_in[6];
  const float* Vz   = (const float*)d_in[7];
  const float* bias = (const float*)d_in[8];
  float* out = (float*)d_out;
  float* Y = (float*)d_ws;   // [32768][128] f32 = 16 MB rank-64 intermediate

  k_proj1<<<dim3(ROWS / 64), dim3(256), 0, stream>>>(x, Vx, Vz, Y);
  k_proj2<<<dim3(T_STEPS, 8), dim3(256), 0, stream>>>(Y, Ux, Uz, bias, out);
  k_recur<<<dim3(BATCH), dim3(1024), 0, stream>>>(h0, Uh, Vh, out);
}

// Round 2
// 4045.982 us; speedup vs baseline: 1.8582x; 1.8582x over previous
//
#include <hip/hip_runtime.h>

#define T_STEPS 2048
#define BATCH   16
#define DIM     1024
#define RANK    64
#define BD      (BATCH * DIM)        // 16384
#define ROWS    (T_STEPS * BATCH)    // 32768

#define DOT4(a, u, v) \
  a = fmaf((u).x, (v).x, fmaf((u).y, (v).y, fmaf((u).z, (v).z, fmaf((u).w, (v).w, (a)))))

// ---------------------------------------------------------------------------
// K1: Y[row][0:64] = x_row . V_x^T ; Y[row][64:128] = x_row . V_z^T
// row = t*16+b. Tiled f32 GEMM: M_TILE=64, N=128, K chunks of 64. (unchanged)
// ---------------------------------------------------------------------------
__global__ __launch_bounds__(256) void k_proj1(const float* __restrict__ x,
                                               const float* __restrict__ Vx,
                                               const float* __restrict__ Vz,
                                               float* __restrict__ Y) {
  __shared__ __align__(16) float Xs[64][64];    // [k][m] 16KB
  __shared__ __align__(16) float Vs[64][128];   // [k][n] 32KB
  const int tid = threadIdx.x;
  const int m0 = blockIdx.x * 64;
  const int ty = tid >> 4;   // m group (16 groups of 4 rows)
  const int tx = tid & 15;   // n group (16 groups of 8 cols)

  float acc[4][8];
#pragma unroll
  for (int i = 0; i < 4; ++i)
#pragma unroll
    for (int j = 0; j < 8; ++j) acc[i][j] = 0.f;

  const int la = tid & 63;   // X loader: row
  const int lb = tid >> 6;   // X loader: k sub-block 0..3
  const int vn = tid & 127;  // V loader: n row
  const int vk = tid >> 7;   // V loader: k half 0..1
  const float* vsrc = (vn < 64) ? (Vx + (size_t)vn * DIM) : (Vz + (size_t)(vn - 64) * DIM);

  for (int kc = 0; kc < DIM; kc += 64) {
    __syncthreads();
#pragma unroll
    for (int q = 0; q < 4; ++q) {
      const float4 v = *reinterpret_cast<const float4*>(x + (size_t)(m0 + la) * DIM + kc + lb * 16 + q * 4);
      const int k = lb * 16 + q * 4;
      Xs[k + 0][la] = v.x; Xs[k + 1][la] = v.y; Xs[k + 2][la] = v.z; Xs[k + 3][la] = v.w;
    }
#pragma unroll
    for (int q = 0; q < 8; ++q) {
      const float4 v = *reinterpret_cast<const float4*>(vsrc + kc + vk * 32 + q * 4);
      const int k = vk * 32 + q * 4;
      Vs[k + 0][vn] = v.x; Vs[k + 1][vn] = v.y; Vs[k + 2][vn] = v.z; Vs[k + 3][vn] = v.w;
    }
    __syncthreads();
#pragma unroll 8
    for (int k = 0; k < 64; ++k) {
      const float4 xm = *reinterpret_cast<const float4*>(&Xs[k][ty * 4]);      // broadcast
      const float4 v0 = *reinterpret_cast<const float4*>(&Vs[k][tx * 8]);
      const float4 v1 = *reinterpret_cast<const float4*>(&Vs[k][tx * 8 + 4]);
      const float xs[4] = {xm.x, xm.y, xm.z, xm.w};
      const float vs[8] = {v0.x, v0.y, v0.z, v0.w, v1.x, v1.y, v1.z, v1.w};
#pragma unroll
      for (int i = 0; i < 4; ++i)
#pragma unroll
        for (int j = 0; j < 8; ++j) acc[i][j] = fmaf(xs[i], vs[j], acc[i][j]);
    }
  }
#pragma unroll
  for (int i = 0; i < 4; ++i) {
    float* dst = Y + (size_t)(m0 + ty * 4 + i) * 128 + tx * 8;
    float4 o0 = {acc[i][0], acc[i][1], acc[i][2], acc[i][3]};
    float4 o1 = {acc[i][4], acc[i][5], acc[i][6], acc[i][7]};
    *reinterpret_cast<float4*>(dst) = o0;
    *reinterpret_cast<float4*>(dst + 4) = o1;
  }
}

// ---------------------------------------------------------------------------
// K2: ux[t,b,d] = Y[t,b,0:64].U_x[d,:] + bias[d]   -> staged into h slot t+1
//     gate[t,b,d] = silu(Y[t,b,64:128].U_z[d,:])   -> staged into out slot t
// v2: 4 timesteps per block (U regs reused 4x). grid (T/4, 8).
// ---------------------------------------------------------------------------
__global__ __launch_bounds__(256, 4) void k_proj2(const float* __restrict__ Y,
                                                  const float* __restrict__ Ux,
                                                  const float* __restrict__ Uz,
                                                  const float* __restrict__ bias,
                                                  float* __restrict__ outbase) {
  __shared__ __align__(16) float Ys[4][16][64];   // 16 KB: [t-local][b][r]
  const int t0 = blockIdx.x * 4;
  const int j = blockIdx.y;
  const bool is_z = (j >= 4);
  const int col = (is_z ? (j - 4) : j) * 256 + threadIdx.x;
  const int roff = is_z ? 64 : 0;

  const float* up = (is_z ? Uz : Ux) + (size_t)col * RANK;
  float4 Uc[16];
#pragma unroll
  for (int q = 0; q < 16; ++q) Uc[q] = *reinterpret_cast<const float4*>(up + q * 4);
  const float bb = is_z ? 0.f : bias[col];

  {
    const int rr = threadIdx.x & 15;   // float4 index within 64-float row
    const int bt = threadIdx.x >> 4;   // 0..15
#pragma unroll
    for (int s = 0; s < 4; ++s) {
      const float4 v = *reinterpret_cast<const float4*>(
          Y + (size_t)((t0 + s) * BATCH + bt) * 128 + roff + rr * 4);
      *reinterpret_cast<float4*>(&Ys[s][bt][rr * 4]) = v;
    }
  }
  __syncthreads();

#pragma unroll 1
  for (int s = 0; s < 4; ++s) {
    const int t = t0 + s;
    float acc[16];
#pragma unroll
    for (int b = 0; b < 16; ++b) acc[b] = 0.f;
#pragma unroll
    for (int q = 0; q < 16; ++q) {
      const float4 u = Uc[q];
#pragma unroll
      for (int b = 0; b < 16; ++b) {
        const float4 y = *reinterpret_cast<const float4*>(&Ys[s][b][q * 4]);  // broadcast
        DOT4(acc[b], u, y);
      }
    }
    if (is_z) {
      float* g = outbase + (size_t)t * BD + col;   // gate into output section
#pragma unroll
      for (int b = 0; b < 16; ++b) {
        const float v = acc[b];
        g[(size_t)b * DIM] = v / (1.f + __expf(-v));   // silu
      }
    } else {
      float* u = outbase + (size_t)T_STEPS * BD + (size_t)(t + 1) * BD + col;  // ux+bias -> h slot t+1
#pragma unroll
      for (int b = 0; b < 16; ++b) u[(size_t)b * DIM] = acc[b] + bb;
    }
  }
}

// ---------------------------------------------------------------------------
// K3: sequential recurrence. 16 blocks (one per batch) x 512 threads (8 waves).
// __launch_bounds__(512,2): 8 waves/CU -> VGPR cap 256 (v1's 1024-thr block
// capped at 128 and spilled ~60 regs -> 6.9ms, VALUBusy 2.6%).
// Thread t owns output dims {t, t+512}: U rows in 128 VGPR.
// Wave w owns V rows 8w..8w+7: rows 0-3 in 64 VGPR, rows 4-7 in LDS (128 KB).
// Lane l owns cols {256j+4l..+3, j=0..3}: h reads are contiguous ds_read_b128.
// Raw s_barrier + lgkmcnt(0) (no vmcnt drain) keeps ux/gate prefetch in flight.
// ---------------------------------------------------------------------------
__device__ __forceinline__ float wave_sum63(float v) {
  // Full 64-lane sum, valid in lane 63. VALU-pipe DPP tree.
  int x;
  x = __builtin_amdgcn_update_dpp(0, __float_as_int(v), 0x111, 0xf, 0xf, true); v += __int_as_float(x); // row_shr:1
  x = __builtin_amdgcn_update_dpp(0, __float_as_int(v), 0x112, 0xf, 0xf, true); v += __int_as_float(x); // row_shr:2
  x = __builtin_amdgcn_update_dpp(0, __float_as_int(v), 0x114, 0xf, 0xf, true); v += __int_as_float(x); // row_shr:4
  x = __builtin_amdgcn_update_dpp(0, __float_as_int(v), 0x118, 0xf, 0xf, true); v += __int_as_float(x); // row_shr:8
  x = __builtin_amdgcn_update_dpp(0, __float_as_int(v), 0x142, 0xa, 0xf, true); v += __int_as_float(x); // bcast15
  x = __builtin_amdgcn_update_dpp(0, __float_as_int(v), 0x143, 0xc, 0xf, true); v += __int_as_float(x); // bcast31
  return v;
}

__device__ __forceinline__ void bar_lds() {
  asm volatile("s_waitcnt lgkmcnt(0)" ::: "memory");
  __builtin_amdgcn_s_barrier();
}

__device__ __forceinline__ float tanh_fast(float x) {
  const float e = __expf(2.f * x);
  return (e - 1.f) / (e + 1.f);
}

__global__ __launch_bounds__(512, 2) void k_recur(const float* __restrict__ h0,
                                                  const float* __restrict__ Uh,
                                                  const float* __restrict__ Vh,
                                                  float* __restrict__ outbase) {
  // LDS: 128KB V rows 4-7 + 4KB h + 256B r = 132.3 KB (1 block/CU)
  __shared__ __align__(16) float4 VL[8][4][4][64];  // [wave][row-4][j][lane]
  __shared__ __align__(16) float hbuf[DIM];
  __shared__ __align__(16) float rbuf[RANK];

  const int tid = threadIdx.x;           // 0..511
  const int w = tid >> 6, l = tid & 63;
  const int b = blockIdx.x;
  const int d0 = tid, d1 = tid + 512;

  float* outsec = outbase;                          // [T][B][D] (gate -> out)
  float* hsec   = outbase + (size_t)T_STEPS * BD;   // [T+1][B][D] (ux -> h)

  // U rows for this thread's two output dims: 32 float4 = 128 VGPR
  float4 U0[16], U1[16];
  {
    const float4* u0p = reinterpret_cast<const float4*>(Uh + (size_t)d0 * RANK);
    const float4* u1p = reinterpret_cast<const float4*>(Uh + (size_t)d1 * RANK);
#pragma unroll
    for (int q = 0; q < 16; ++q) { U0[q] = u0p[q]; U1[q] = u1p[q]; }
  }

  // V rows 8w..8w+3 -> 16 float4 VGPR; rows 8w+4..8w+7 -> LDS
  float4 Vr[4][4];
  {
    const float* vb = Vh + (size_t)(8 * w) * DIM + 4 * l;
#pragma unroll
    for (int rr = 0; rr < 4; ++rr)
#pragma unroll
      for (int j = 0; j < 4; ++j)
        Vr[rr][j] = *reinterpret_cast<const float4*>(vb + (size_t)rr * DIM + j * 256);
#pragma unroll
    for (int rr = 0; rr < 4; ++rr)
#pragma unroll
      for (int j = 0; j < 4; ++j)
        VL[w][rr][j][l] = *reinterpret_cast<const float4*>(vb + (size_t)(4 + rr) * DIM + j * 256);
  }

  // h[0] = h0
  const float h00 = h0[(size_t)b * DIM + d0];
  const float h01 = h0[(size_t)b * DIM + d1];
  hbuf[d0] = h00; hbuf[d1] = h01;
  hsec[(size_t)b * DIM + d0] = h00;
  hsec[(size_t)b * DIM + d1] = h01;

  float* hw = hsec + BD + (size_t)b * DIM;       // h slot t+1 (holds ux(t) before write)
  float* ow = outsec + (size_t)b * DIM;          // out slot t (holds gate(t) before write)
  float ux0 = hw[d0], ux1 = hw[d1];
  float gt0 = ow[d0], gt1 = ow[d1];

  bar_lds();

  const float4* hb4 = reinterpret_cast<const float4*>(hbuf);
  for (int t = 0; t < T_STEPS; ++t) {
    // ---------- phase 1: r[64] = V_h . h ----------
    float a0 = 0.f, a1 = 0.f, a2 = 0.f, a3 = 0.f;
    float a4 = 0.f, a5 = 0.f, a6 = 0.f, a7 = 0.f;
#pragma unroll
    for (int j = 0; j < 4; ++j) {
      const float4 hv = hb4[j * 64 + l];          // contiguous b128, conflict-free
      DOT4(a0, Vr[0][j], hv);
      DOT4(a1, Vr[1][j], hv);
      DOT4(a2, Vr[2][j], hv);
      DOT4(a3, Vr[3][j], hv);
      const float4 w4 = VL[w][0][j][l]; DOT4(a4, w4, hv);
      const float4 w5 = VL[w][1][j][l]; DOT4(a5, w5, hv);
      const float4 w6 = VL[w][2][j][l]; DOT4(a6, w6, hv);
      const float4 w7 = VL[w][3][j][l]; DOT4(a7, w7, hv);
    }
    const float r0 = wave_sum63(a0);
    const float r1 = wave_sum63(a1);
    const float r2 = wave_sum63(a2);
    const float r3 = wave_sum63(a3);
    const float r4 = wave_sum63(a4);
    const float r5 = wave_sum63(a5);
    const float r6 = wave_sum63(a6);
    const float r7 = wave_sum63(a7);
    if (l == 63) {
      float4* rb = reinterpret_cast<float4*>(rbuf);
      rb[2 * w + 0] = make_float4(r0, r1, r2, r3);
      rb[2 * w + 1] = make_float4(r4, r5, r6, r7);
    }
    bar_lds();

    // ---------- phase 2: h_new = tanh(U_h . r + ux(+b)) ----------
    float A0 = ux0, A1 = ux1;
    const float4* r4p = reinterpret_cast<const float4*>(rbuf);
#pragma unroll
    for (int q = 0; q < 16; ++q) {
      const float4 rr = r4p[q];                   // uniform addr -> broadcast
      DOT4(A0, U0[q], rr);
      DOT4(A1, U1[q], rr);
    }
    const float hn0 = tanh_fast(A0);
    const float hn1 = tanh_fast(A1);

    hw[d0] = hn0;            hw[d1] = hn1;             // overwrites consumed ux slot
    ow[d0] = hn0 * gt0;      ow[d1] = hn1 * gt1;       // overwrites consumed gate slot

    if (t + 1 < T_STEPS) {   // one-step-ahead prefetch, stays in flight across barriers
      ux0 = hw[BD + d0]; ux1 = hw[BD + d1];
      gt0 = ow[BD + d0]; gt1 = ow[BD + d1];
    }
    hbuf[d0] = hn0; hbuf[d1] = hn1;
    bar_lds();
    hw += BD; ow += BD;
  }
}

extern "C" void kernel_launch(void* const* d_in, const int* in_sizes, int n_in,
                              void* d_out, int out_size, void* d_ws, size_t ws_size,
                              hipStream_t stream) {
  const float* x    = (const float*)d_in[0];
  const float* h0   = (const float*)d_in[1];
  const float* Uh   = (const float*)d_in[2];
  const float* Vh   = (const float*)d_in[3];
  const float* Ux   = (const float*)d_in[4];
  const float* Vx   = (const float*)d_in[5];
  const float* Uz   = (const float*)d_in[6];
  const float* Vz   = (const float*)d_in[7];
  const float* bias = (const float*)d_in[8];
  float* out = (float*)d_out;
  float* Y = (float*)d_ws;   // [32768][128] f32 = 16 MB rank-64 intermediate

  k_proj1<<<dim3(ROWS / 64), dim3(256), 0, stream>>>(x, Vx, Vz, Y);
  k_proj2<<<dim3(T_STEPS / 4, 8), dim3(256), 0, stream>>>(Y, Ux, Uz, bias, out);
  k_recur<<<dim3(BATCH), dim3(512), 0, stream>>>(h0, Uh, Vh, out);
}